// Round 7
// baseline (189.286 us; speedup 1.0000x reference)
//
#include <hip/hip_runtime.h>
#include <math.h>

#define LOG2PI_F   1.8378770664093453f
#define LOGPI_F    1.1447298858494002f
#define LOG2_F     0.6931471805599453f
#define L2E_F      1.4426950408889634f
#define ERF3OS2    0.9973002039367398f   // erf(3/sqrt(2)), wf = 3.0 (compile-time)
#define WF         3.0f
#define NMC        1024
#define NTOT       3072                  // 3 * NMC real entries
#define FCAP       384                   // static front capacity (needs-bm region)
#define BCAP       2944                  // static back capacity (1-exp region)
#define NCAP       (FCAP + BCAP)         // 3328 = NTOT + 256 dummies
#define NPAIRS     (NCAP / 2)            // 1664
#define FPAIRS     (FCAP / 2)            // 192
#define BPAIRS     (BCAP / 2)            // 1472
#define LOGN_F     6.9314718055994531f   // log(1024)
#define LOGGAMMA15 (-0.12078223763524522f)
#define YMIN_F     0.01f                 // global lower bound on y
#define QSKIP_F    8.0f                  // skip bm when 2*YMIN*gc >= 8 (rel err < 2^-8)
#define ZDUMMY     (-1.0e9f)

typedef float v2f __attribute__((ext_vector_type(2)));

#if defined(__has_builtin)
#if __has_builtin(__builtin_amdgcn_exp2f)
#define EXP2(v) __builtin_amdgcn_exp2f(v)
#else
#define EXP2(v) __expf((v) * LOG2_F)
#endif
#else
#define EXP2(v) __expf((v) * LOG2_F)
#endif

// ---------------- Kernel A: fused + partitioned + paired table ----------------
// (identical to R6 — validated) Entry {txc, gc, zc}: txc = inv_sn2*tx*L2E ;
// gc = 2*inv_sn2*G*L2E ; zc = (B - 0.5*inv_sn2*tx^2 - inv_sn2*G^2)*L2E,
// B = -logG + lptx + log(I_diff) - logN + lw_c.
// bp = Cm + x*txc + y*gc + zc ; bm = bp - 2*y*gc ; term = 2^bp - 2^bm.
// Front [0,FCAP): bm can matter; back [FCAP,NCAP): bm provably negligible.
// Dummies zc=-1e9 -> exp2 -> 0. Paired layout for v_pk math.
__global__ void precompute_kernel(const float* __restrict__ ku12,
                                  const float* __restrict__ ku23,
                                  const float* __restrict__ ku13,
                                  const float* __restrict__ sbp,
                                  const float* __restrict__ snp,
                                  const float* __restrict__ I1p,
                                  const float* __restrict__ I2p,
                                  const float* __restrict__ I3p,
                                  const float* __restrict__ w,
                                  float4* __restrict__ tabA,
                                  float2* __restrict__ tabZ,
                                  float* __restrict__ hdr,
                                  float* __restrict__ out) {
    __shared__ float sTx[NCAP], sG[NCAP], sZ[NCAP];
    __shared__ int cF, cB;
    const int n = threadIdx.x;           // 1024 threads, 1 block
    const int lane = n & 63;
    if (n == 0) { cF = 0; cB = 0; }
    __syncthreads();

    const float sigma_b = sbp[0], sigma_n = snp[0];
    const float I1 = I1p[0], I2 = I2p[0], I3 = I3p[0];
    const float inv_sn2 = 1.0f / (sigma_n * sigma_n);

    float wv[6];
    #pragma unroll
    for (int i = 0; i < 6; ++i) wv[i] = w[i];
    float wm = wv[0];
    #pragma unroll
    for (int i = 1; i < 6; ++i) wm = fmaxf(wm, wv[i]);
    float wsum = 0.f;
    #pragma unroll
    for (int i = 0; i < 6; ++i) wsum += __expf(wv[i] - wm);
    const float lsew = wm + __logf(wsum);

    const float* kus[3] = {ku12, ku23, ku13};
    const float Ias[3] = {I1, I2, I1};
    const float Ibs[3] = {I2, I3, I3};
    const float gb = rsqrtf(2.0f * (float)M_PI * sigma_b * sigma_b);

    #pragma unroll
    for (int c = 0; c < 3; ++c) {
        const float Ia = Ias[c], Ib = Ibs[c];
        const float gap = Ib - Ia;
        const float I_min  = Ia + 0.5f * gap * (1.0f - ERF3OS2);
        const float I_diff = gap * ERF3OS2;
        const float add_c  = __logf(I_diff) - LOGN_F + (wv[3 + c] - lsew);
        const float ku = kus[c][n];
        const float tx = ku * I_diff + I_min;
        const float v  = 2.0f * (tx - Ia) / gap - 1.0f;
        const float ei = erfinvf(v);
        const float ei2 = ei * ei;
        const float G   = gap * gb * __expf(-ei2);
        const float lptx = -__logf(2.0f * WF * gap) + 0.5f * LOG2PI_F + ei2;
        const float B = -__logf(G) + lptx + add_c;

        const float txc = inv_sn2 * tx * L2E_F;
        const float gc  = 2.0f * inv_sn2 * G * L2E_F;
        const float zc  = (B - 0.5f * inv_sn2 * tx * tx - inv_sn2 * G * G) * L2E_F;

        const bool needs = (2.0f * YMIN_F * gc < QSKIP_F);
        const unsigned long long mask = __ballot(needs);
        const int nf = __popcll(mask);
        const int rankF = __popcll(mask & ((1ull << lane) - 1ull));
        const int rankB = lane - rankF;
        int bF = 0, bB = 0;
        if (lane == 0) { bF = atomicAdd(&cF, nf); bB = atomicAdd(&cB, 64 - nf); }
        bF = __shfl(bF, 0); bB = __shfl(bB, 0);
        int idx;
        if (needs) {
            idx = bF + rankF;
            if (idx >= FCAP) idx = FCAP + atomicAdd(&cB, 1);   // fallback (never expected)
        } else {
            idx = FCAP + bB + rankB;
            if (idx >= NCAP) idx = atomicAdd(&cF, 1);          // fallback (never expected)
        }
        if (idx >= 0 && idx < NCAP) { sTx[idx] = txc; sG[idx] = gc; sZ[idx] = zc; }
    }
    __syncthreads();

    const int kF = (cF < FCAP) ? cF : FCAP;
    for (int i = n + kF; i < FCAP; i += 1024) { sTx[i] = 0.f; sG[i] = 0.f; sZ[i] = ZDUMMY; }
    const int backEnd = FCAP + cB;
    for (int i = n + backEnd; i < NCAP; i += 1024) { sTx[i] = 0.f; sG[i] = 0.f; sZ[i] = ZDUMMY; }
    __syncthreads();

    for (int p = n; p < NPAIRS; p += 1024) {
        const int e0 = 2 * p, e1 = 2 * p + 1;
        tabA[p] = make_float4(sTx[e0], sTx[e1], sG[e0], sG[e1]);
        tabZ[p] = make_float2(sZ[e0], sZ[e1]);
    }

    if (n == 0) {
        const float lsn = __logf(sigma_n);
        hdr[0] = inv_sn2;
        hdr[1] = -2.f * lsn - 0.5f * LOG2PI_F - 0.5f * LOGPI_F;        // C_A
        hdr[2] = LOG2_F - LOGGAMMA15 - 4.f * lsn - 0.5f * LOG2PI_F;    // K_int
        hdr[3] = I1; hdr[4] = I2; hdr[5] = I3;
        hdr[6] = wv[0] - lsew; hdr[7] = wv[1] - lsew; hdr[8] = wv[2] - lsew;
        out[0] = 0.f;
    }
}

// ---------------- Kernel B: main loop (static, packed, VMEM-forced) ----------------
// Block = 512 threads = 8 waves. Lane -> point m; wave w owns a contiguous
// slice of pairs. Table base pointers are offset by an OPAQUE VGPR zero so the
// compiler must emit vector global loads (vmcnt, in-order partial waits) instead
// of s_load batches that require a full lgkmcnt(0) drain (R6's stall).
#define WAVES 8
#define FPW   (FPAIRS / WAVES)   // 24 front pairs per wave
#define BPW   (BPAIRS / WAVES)   // 184 back pairs per wave
#define BT    4                  // pairs staged per batch (8 loads in flight)

__global__ __launch_bounds__(512, 4) void
main_kernel(const float* __restrict__ xg, const float* __restrict__ yg,
            const float4* __restrict__ tabA, const float2* __restrict__ tabZ,
            const float* __restrict__ hdr, float* __restrict__ out, int M) {
    const int lane = threadIdx.x & 63;
    const int wave = threadIdx.x >> 6;
    const int m = blockIdx.x * 64 + lane;
    const bool valid = (m < M);
    const float x = valid ? xg[m] : 0.5f;
    const float y = valid ? yg[m] : 0.5f;

    const float inv_sn2 = hdr[0];
    const float Cm = -(fmaf(0.5f * x, x, y * y)) * inv_sn2 * L2E_F;

    const v2f x2  = {x, x};
    const v2f y2  = {y, y};
    const v2f Cm2 = {Cm, Cm};
    const v2f n2y = {-2.f * y, -2.f * y};

    // opaque zero in a VGPR: forces per-lane (vector) addressing for table loads
    int zz;
    asm volatile("v_mov_b32 %0, 0" : "=v"(zz));
    const float4* tA = tabA + zz;
    const float2* tZ = tabZ + zz;

    v2f accP = {0.f, 0.f}, accM = {0.f, 0.f}, accA = {0.f, 0.f};

    // front region: bm matters -> 2 exps per entry
    {
        int base = wave * FPW;
        for (int jb = 0; jb < FPW / BT; ++jb) {
            float4 a[BT]; float2 z[BT];
            #pragma unroll
            for (int u = 0; u < BT; ++u) { a[u] = tA[base + u]; z[u] = tZ[base + u]; }
            #pragma unroll
            for (int u = 0; u < BT; ++u) {
                const v2f tx2 = {a[u].x, a[u].y};
                const v2f g2  = {a[u].z, a[u].w};
                const v2f z2  = {z[u].x, z[u].y};
                const v2f t1 = __builtin_elementwise_fma(x2, tx2, Cm2);
                const v2f t2 = __builtin_elementwise_fma(y2, g2, t1);
                const v2f bp = t2 + z2;
                const v2f bm = __builtin_elementwise_fma(n2y, g2, bp);
                const v2f ea = {EXP2(bp[0]), EXP2(bp[1])};
                const v2f eb = {EXP2(bm[0]), EXP2(bm[1])};
                accP += ea;
                accM += eb;
            }
            base += BT;
        }
    }
    // back region: bm provably negligible -> 1 exp per entry
    {
        int base = FPAIRS + wave * BPW;
        for (int jb = 0; jb < BPW / BT; ++jb) {
            float4 a[BT]; float2 z[BT];
            #pragma unroll
            for (int u = 0; u < BT; ++u) { a[u] = tA[base + u]; z[u] = tZ[base + u]; }
            #pragma unroll
            for (int u = 0; u < BT; ++u) {
                const v2f tx2 = {a[u].x, a[u].y};
                const v2f g2  = {a[u].z, a[u].w};
                const v2f z2  = {z[u].x, z[u].y};
                const v2f t1 = __builtin_elementwise_fma(x2, tx2, Cm2);
                const v2f t2 = __builtin_elementwise_fma(y2, g2, t1);
                const v2f bp = t2 + z2;
                const v2f ea = {EXP2(bp[0]), EXP2(bp[1])};
                accA += ea;
            }
            base += BT;
        }
    }

    __shared__ float pac[WAVES][64];
    const v2f tot = (accP - accM) + accA;
    pac[wave][lane] = tot[0] + tot[1];
    __syncthreads();

    if (wave == 0) {
        const float ly = __logf(y);
        const float A_m = hdr[1] + ly;
        const float base_int = hdr[2] + 2.f * ly - y * y * inv_sn2;
        float vals[4];
        #pragma unroll
        for (int c = 0; c < 3; ++c) {
            const float dxi = x - hdr[3 + c];
            vals[c] = hdr[6 + c] + base_int - 0.5f * dxi * dxi * inv_sn2;
        }
        float s = 0.f;
        #pragma unroll
        for (int wv2 = 0; wv2 < WAVES; ++wv2) s += pac[wv2][lane];
        vals[3] = A_m + __logf(fmaxf(s, 1e-38f));

        float mm = vals[0];
        #pragma unroll
        for (int i = 1; i < 4; ++i) mm = fmaxf(mm, vals[i]);
        float se = 0.f;
        #pragma unroll
        for (int i = 0; i < 4; ++i) se += __expf(vals[i] - mm);
        const float log_mix = mm + __logf(se);
        float contrib = valid ? -log_mix : 0.f;
        #pragma unroll
        for (int off = 32; off > 0; off >>= 1) contrib += __shfl_down(contrib, off);
        if (lane == 0) atomicAdd(out, contrib);
    }
}

extern "C" void kernel_launch(void* const* d_in, const int* in_sizes, int n_in,
                              void* d_out, int out_size, void* d_ws, size_t ws_size,
                              hipStream_t stream) {
    const float* x    = (const float*)d_in[0];
    const float* y    = (const float*)d_in[1];
    const float* ku12 = (const float*)d_in[2];
    const float* ku23 = (const float*)d_in[3];
    const float* ku13 = (const float*)d_in[4];
    const float* sb   = (const float*)d_in[5];
    const float* sn   = (const float*)d_in[6];
    const float* I1   = (const float*)d_in[7];
    const float* I2   = (const float*)d_in[8];
    const float* I3   = (const float*)d_in[9];
    const float* w    = (const float*)d_in[10];
    const int M = in_sizes[0];

    float4* tabA = (float4*)d_ws;                                        // 1664*16B
    float2* tabZ = (float2*)((char*)d_ws + NPAIRS * sizeof(float4));     // 1664*8B
    float*  hdr  = (float*)((char*)d_ws + NPAIRS * (sizeof(float4) + sizeof(float2)));
    float*  out  = (float*)d_out;

    precompute_kernel<<<1, NMC, 0, stream>>>(ku12, ku23, ku13, sb, sn, I1, I2, I3, w,
                                             tabA, tabZ, hdr, out);
    const int blocks = (M + 63) / 64;
    main_kernel<<<blocks, 512, 0, stream>>>(x, y, tabA, tabZ, hdr, out, M);
}

// Round 8
// 69.305 us; speedup vs baseline: 2.7312x; 2.7312x over previous
//
#include <hip/hip_runtime.h>
#include <math.h>

#define LOG2PI_F   1.8378770664093453f
#define LOGPI_F    1.1447298858494002f
#define LOG2_F     0.6931471805599453f
#define L2E_F      1.4426950408889634f
#define ERF3OS2    0.9973002039367398f   // erf(3/sqrt(2)), wf = 3.0 (compile-time)
#define WF         3.0f
#define NMC        1024
#define NTOT       3072                  // 3 * NMC real entries
#define FCAP       384                   // static front capacity (needs-bm region)
#define BCAP       2944                  // static back capacity (1-exp region)
#define NCAP       (FCAP + BCAP)         // 3328 = NTOT + 256 dummies
#define NPAIRS     (NCAP / 2)            // 1664
#define FPAIRS     (FCAP / 2)            // 192
#define BPAIRS     (BCAP / 2)            // 1472
#define LOGN_F     6.9314718055994531f   // log(1024)
#define LOGGAMMA15 (-0.12078223763524522f)
#define YMIN_F     0.01f                 // global lower bound on y
#define QSKIP_F    8.0f                  // skip bm when 2*YMIN*gc >= 8 (rel err < 2^-8)
#define ZDUMMY     (-1.0e9f)

typedef float v2f __attribute__((ext_vector_type(2)));

#if defined(__has_builtin)
#if __has_builtin(__builtin_amdgcn_exp2f)
#define EXP2(v) __builtin_amdgcn_exp2f(v)
#else
#define EXP2(v) __expf((v) * LOG2_F)
#endif
#else
#define EXP2(v) __expf((v) * LOG2_F)
#endif

// ---------------- Kernel A: fused + partitioned + paired table ----------------
// (identical to R6 — validated) Entry {txc, gc, zc}: txc = inv_sn2*tx*L2E ;
// gc = 2*inv_sn2*G*L2E ; zc = (B - 0.5*inv_sn2*tx^2 - inv_sn2*G^2)*L2E,
// B = -logG + lptx + log(I_diff) - logN + lw_c.
// bp = Cm + x*txc + y*gc + zc ; bm = bp - 2*y*gc ; term = 2^bp - 2^bm.
// Front [0,FCAP): bm can matter; back [FCAP,NCAP): bm provably negligible.
// Dummies zc=-1e9 -> exp2 -> 0. Paired layout for v_pk math.
__global__ void precompute_kernel(const float* __restrict__ ku12,
                                  const float* __restrict__ ku23,
                                  const float* __restrict__ ku13,
                                  const float* __restrict__ sbp,
                                  const float* __restrict__ snp,
                                  const float* __restrict__ I1p,
                                  const float* __restrict__ I2p,
                                  const float* __restrict__ I3p,
                                  const float* __restrict__ w,
                                  float4* __restrict__ tabA,
                                  float2* __restrict__ tabZ,
                                  float* __restrict__ hdr,
                                  float* __restrict__ out) {
    __shared__ float sTx[NCAP], sG[NCAP], sZ[NCAP];
    __shared__ int cF, cB;
    const int n = threadIdx.x;           // 1024 threads, 1 block
    const int lane = n & 63;
    if (n == 0) { cF = 0; cB = 0; }
    __syncthreads();

    const float sigma_b = sbp[0], sigma_n = snp[0];
    const float I1 = I1p[0], I2 = I2p[0], I3 = I3p[0];
    const float inv_sn2 = 1.0f / (sigma_n * sigma_n);

    float wv[6];
    #pragma unroll
    for (int i = 0; i < 6; ++i) wv[i] = w[i];
    float wm = wv[0];
    #pragma unroll
    for (int i = 1; i < 6; ++i) wm = fmaxf(wm, wv[i]);
    float wsum = 0.f;
    #pragma unroll
    for (int i = 0; i < 6; ++i) wsum += __expf(wv[i] - wm);
    const float lsew = wm + __logf(wsum);

    const float* kus[3] = {ku12, ku23, ku13};
    const float Ias[3] = {I1, I2, I1};
    const float Ibs[3] = {I2, I3, I3};
    const float gb = rsqrtf(2.0f * (float)M_PI * sigma_b * sigma_b);

    #pragma unroll
    for (int c = 0; c < 3; ++c) {
        const float Ia = Ias[c], Ib = Ibs[c];
        const float gap = Ib - Ia;
        const float I_min  = Ia + 0.5f * gap * (1.0f - ERF3OS2);
        const float I_diff = gap * ERF3OS2;
        const float add_c  = __logf(I_diff) - LOGN_F + (wv[3 + c] - lsew);
        const float ku = kus[c][n];
        const float tx = ku * I_diff + I_min;
        const float v  = 2.0f * (tx - Ia) / gap - 1.0f;
        const float ei = erfinvf(v);
        const float ei2 = ei * ei;
        const float G   = gap * gb * __expf(-ei2);
        const float lptx = -__logf(2.0f * WF * gap) + 0.5f * LOG2PI_F + ei2;
        const float B = -__logf(G) + lptx + add_c;

        const float txc = inv_sn2 * tx * L2E_F;
        const float gc  = 2.0f * inv_sn2 * G * L2E_F;
        const float zc  = (B - 0.5f * inv_sn2 * tx * tx - inv_sn2 * G * G) * L2E_F;

        const bool needs = (2.0f * YMIN_F * gc < QSKIP_F);
        const unsigned long long mask = __ballot(needs);
        const int nf = __popcll(mask);
        const int rankF = __popcll(mask & ((1ull << lane) - 1ull));
        const int rankB = lane - rankF;
        int bF = 0, bB = 0;
        if (lane == 0) { bF = atomicAdd(&cF, nf); bB = atomicAdd(&cB, 64 - nf); }
        bF = __shfl(bF, 0); bB = __shfl(bB, 0);
        int idx;
        if (needs) {
            idx = bF + rankF;
            if (idx >= FCAP) idx = FCAP + atomicAdd(&cB, 1);   // fallback (never expected)
        } else {
            idx = FCAP + bB + rankB;
            if (idx >= NCAP) idx = atomicAdd(&cF, 1);          // fallback (never expected)
        }
        if (idx >= 0 && idx < NCAP) { sTx[idx] = txc; sG[idx] = gc; sZ[idx] = zc; }
    }
    __syncthreads();

    const int kF = (cF < FCAP) ? cF : FCAP;
    for (int i = n + kF; i < FCAP; i += 1024) { sTx[i] = 0.f; sG[i] = 0.f; sZ[i] = ZDUMMY; }
    const int backEnd = FCAP + cB;
    for (int i = n + backEnd; i < NCAP; i += 1024) { sTx[i] = 0.f; sG[i] = 0.f; sZ[i] = ZDUMMY; }
    __syncthreads();

    for (int p = n; p < NPAIRS; p += 1024) {
        const int e0 = 2 * p, e1 = 2 * p + 1;
        tabA[p] = make_float4(sTx[e0], sTx[e1], sG[e0], sG[e1]);
        tabZ[p] = make_float2(sZ[e0], sZ[e1]);
    }

    if (n == 0) {
        const float lsn = __logf(sigma_n);
        hdr[0] = inv_sn2;
        hdr[1] = -2.f * lsn - 0.5f * LOG2PI_F - 0.5f * LOGPI_F;        // C_A
        hdr[2] = LOG2_F - LOGGAMMA15 - 4.f * lsn - 0.5f * LOG2PI_F;    // K_int
        hdr[3] = I1; hdr[4] = I2; hdr[5] = I3;
        hdr[6] = wv[0] - lsew; hdr[7] = wv[1] - lsew; hdr[8] = wv[2] - lsew;
        out[0] = 0.f;
    }
}

// ---------------- Kernel B: main loop (m-tiled, scalar-load batches) ----------------
// Block = 512 threads = 8 waves covering MBLK = 128 m-points (T=2 per thread:
// m = mb + t*64 + lane). Each wave owns 1/8 of the pairs; batch of BT pairs is
// fetched via scalar loads (wave-uniform index), then consumed by T points ->
// the lgkmcnt(0) drain is amortized 2x. Wave-dependent batch-order rotation
// de-correlates the drains across waves (static trip counts!).
#define WAVES 8
#define T     2
#define MBLK  (64 * T)            // 128
#define FPW   (FPAIRS / WAVES)    // 24 front pairs per wave
#define BPW   (BPAIRS / WAVES)    // 184 back pairs per wave
#define BT    8                   // pairs per scalar batch
#define NBF   (FPW / BT)          // 3
#define NBB   (BPW / BT)          // 23

__global__ __launch_bounds__(512) void
main_kernel(const float* __restrict__ xg, const float* __restrict__ yg,
            const float4* __restrict__ tabA, const float2* __restrict__ tabZ,
            const float* __restrict__ hdr, float* __restrict__ out, int M) {
    const int lane = threadIdx.x & 63;
    const int wave = threadIdx.x >> 6;
    const int wv0  = __builtin_amdgcn_readfirstlane(wave);
    const int mb = blockIdx.x * MBLK;

    const float inv_sn2 = hdr[0];

    float xv[T], yv[T];
    bool  val[T];
    v2f x2[T], y2[T], Cm2[T], n2y[T];
    #pragma unroll
    for (int t = 0; t < T; ++t) {
        const int m = mb + t * 64 + lane;
        val[t] = (m < M);
        xv[t] = val[t] ? xg[m] : 0.5f;
        yv[t] = val[t] ? yg[m] : 0.5f;
        const float Cm = -(fmaf(0.5f * xv[t], xv[t], yv[t] * yv[t])) * inv_sn2 * L2E_F;
        x2[t]  = (v2f){xv[t], xv[t]};
        y2[t]  = (v2f){yv[t], yv[t]};
        Cm2[t] = (v2f){Cm, Cm};
        n2y[t] = (v2f){-2.f * yv[t], -2.f * yv[t]};
    }

    v2f accF[T], accB[T];
    #pragma unroll
    for (int t = 0; t < T; ++t) { accF[t] = (v2f){0.f, 0.f}; accB[t] = (v2f){0.f, 0.f}; }

    // ---- front region: 2 exps per entry ----
    {
        int fb = wv0 % NBF;                       // stagger start batch
        for (int jb = 0; jb < NBF; ++jb) {        // static trip count
            const int base = wv0 * FPW + fb * BT;
            float4 a[BT]; float2 z[BT];
            #pragma unroll
            for (int u = 0; u < BT; ++u) { a[u] = tabA[base + u]; z[u] = tabZ[base + u]; }
            #pragma unroll
            for (int u = 0; u < BT; ++u) {
                const v2f tx2 = {a[u].x, a[u].y};
                const v2f g2  = {a[u].z, a[u].w};
                const v2f z2  = {z[u].x, z[u].y};
                #pragma unroll
                for (int t = 0; t < T; ++t) {
                    const v2f t1 = __builtin_elementwise_fma(x2[t], tx2, Cm2[t]);
                    const v2f t2 = __builtin_elementwise_fma(y2[t], g2, t1);
                    const v2f bp = t2 + z2;
                    const v2f bm = __builtin_elementwise_fma(n2y[t], g2, bp);
                    const v2f ea = {EXP2(bp[0]), EXP2(bp[1])};
                    const v2f eb = {EXP2(bm[0]), EXP2(bm[1])};
                    accF[t] += (ea - eb);
                }
            }
            fb = (fb + 1 == NBF) ? 0 : fb + 1;
        }
    }
    // ---- back region: 1 exp per entry ----
    {
        int bb = (wv0 * 3) % NBB;                 // stagger start batch
        for (int jb = 0; jb < NBB; ++jb) {        // static trip count
            const int base = FPAIRS + wv0 * BPW + bb * BT;
            float4 a[BT]; float2 z[BT];
            #pragma unroll
            for (int u = 0; u < BT; ++u) { a[u] = tabA[base + u]; z[u] = tabZ[base + u]; }
            #pragma unroll
            for (int u = 0; u < BT; ++u) {
                const v2f tx2 = {a[u].x, a[u].y};
                const v2f g2  = {a[u].z, a[u].w};
                const v2f z2  = {z[u].x, z[u].y};
                #pragma unroll
                for (int t = 0; t < T; ++t) {
                    const v2f t1 = __builtin_elementwise_fma(x2[t], tx2, Cm2[t]);
                    const v2f t2 = __builtin_elementwise_fma(y2[t], g2, t1);
                    const v2f bp = t2 + z2;
                    const v2f ea = {EXP2(bp[0]), EXP2(bp[1])};
                    accB[t] += ea;
                }
            }
            bb = (bb + 1 == NBB) ? 0 : bb + 1;
        }
    }

    __shared__ float pac[WAVES][T][64];
    #pragma unroll
    for (int t = 0; t < T; ++t) {
        const v2f tot = accF[t] + accB[t];
        pac[wave][t][lane] = tot[0] + tot[1];
    }
    __syncthreads();

    if (wave < T) {
        const int t = wave;                       // this thread holds x/y for (t, lane)
        const float x = xv[t], y = yv[t];
        const float ly = __logf(y);
        const float A_m = hdr[1] + ly;
        const float base_int = hdr[2] + 2.f * ly - y * y * inv_sn2;
        float vals[4];
        #pragma unroll
        for (int c = 0; c < 3; ++c) {
            const float dxi = x - hdr[3 + c];
            vals[c] = hdr[6 + c] + base_int - 0.5f * dxi * dxi * inv_sn2;
        }
        float s = 0.f;
        #pragma unroll
        for (int wq = 0; wq < WAVES; ++wq) s += pac[wq][t][lane];
        vals[3] = A_m + __logf(fmaxf(s, 1e-38f));

        float mm = vals[0];
        #pragma unroll
        for (int i = 1; i < 4; ++i) mm = fmaxf(mm, vals[i]);
        float se = 0.f;
        #pragma unroll
        for (int i = 0; i < 4; ++i) se += __expf(vals[i] - mm);
        const float log_mix = mm + __logf(se);
        float contrib = val[t] ? -log_mix : 0.f;
        #pragma unroll
        for (int off = 32; off > 0; off >>= 1) contrib += __shfl_down(contrib, off);
        if (lane == 0) atomicAdd(out, contrib);
    }
}

extern "C" void kernel_launch(void* const* d_in, const int* in_sizes, int n_in,
                              void* d_out, int out_size, void* d_ws, size_t ws_size,
                              hipStream_t stream) {
    const float* x    = (const float*)d_in[0];
    const float* y    = (const float*)d_in[1];
    const float* ku12 = (const float*)d_in[2];
    const float* ku23 = (const float*)d_in[3];
    const float* ku13 = (const float*)d_in[4];
    const float* sb   = (const float*)d_in[5];
    const float* sn   = (const float*)d_in[6];
    const float* I1   = (const float*)d_in[7];
    const float* I2   = (const float*)d_in[8];
    const float* I3   = (const float*)d_in[9];
    const float* w    = (const float*)d_in[10];
    const int M = in_sizes[0];

    float4* tabA = (float4*)d_ws;                                        // 1664*16B
    float2* tabZ = (float2*)((char*)d_ws + NPAIRS * sizeof(float4));     // 1664*8B
    float*  hdr  = (float*)((char*)d_ws + NPAIRS * (sizeof(float4) + sizeof(float2)));
    float*  out  = (float*)d_out;

    precompute_kernel<<<1, NMC, 0, stream>>>(ku12, ku23, ku13, sb, sn, I1, I2, I3, w,
                                             tabA, tabZ, hdr, out);
    const int blocks = (M + MBLK - 1) / MBLK;
    main_kernel<<<blocks, 512, 0, stream>>>(x, y, tabA, tabZ, hdr, out, M);
}